// Round 7
// baseline (193.731 us; speedup 1.0000x reference)
//
#include <hip/hip_runtime.h>

#define NUM_GRAPHS 512
#define N_NODES 100000
#define N_EDGES 1600000
#define D_NODE 128
#define D_EDGE 32
#define D_OUT 64

#define NSET 8                      // bucket sets; set = blockIdx&7 ~ XCD under round-robin
#define CAP 768                     // slots per (set,graph) bin; mean ~391, sigma ~20
#define NBINS (NSET * NUM_GRAPHS)   // 4096

// ---------------- kernel 0: zero the cursors (graph-capture-safe init) ----------------
__global__ __launch_bounds__(256) void zero_kernel(int* __restrict__ cursors) {
    const int t = blockIdx.x * 256 + threadIdx.x;
    if (t < NBINS) cursors[t] = 0;
}

// ---------------- kernel 1: scatter edge ids into per-(set,graph) buckets -------------
// 4 edges per thread: int4 col load + 4 independent gather->atomic->store chains (MLP).
__global__ __launch_bounds__(256) void scatter_kernel(const int* __restrict__ col,
                                                      const int* __restrict__ batch,
                                                      int* __restrict__ cursors,
                                                      int* __restrict__ bucket) {
    const int base = (blockIdx.x * 256 + threadIdx.x) * 4;
    const int set = blockIdx.x & (NSET - 1);     // blocks round-robin XCDs
    if (base + 3 < N_EDGES) {
        const int4 c = *reinterpret_cast<const int4*>(col + base);
        // 4 independent gathers (batch is L2/L3-resident)
        const int g0 = batch[c.x];
        const int g1 = batch[c.y];
        const int g2 = batch[c.z];
        const int g3 = batch[c.w];
        const int bin0 = set * NUM_GRAPHS + g0;
        const int bin1 = set * NUM_GRAPHS + g1;
        const int bin2 = set * NUM_GRAPHS + g2;
        const int bin3 = set * NUM_GRAPHS + g3;
        // 4 independent atomic->store chains
        const int s0 = atomicAdd(&cursors[bin0], 1);
        const int s1 = atomicAdd(&cursors[bin1], 1);
        const int s2 = atomicAdd(&cursors[bin2], 1);
        const int s3 = atomicAdd(&cursors[bin3], 1);
        if (s0 < CAP) bucket[(size_t)bin0 * CAP + s0] = base + 0;
        if (s1 < CAP) bucket[(size_t)bin1 * CAP + s1] = base + 1;
        if (s2 < CAP) bucket[(size_t)bin2 * CAP + s2] = base + 2;
        if (s3 < CAP) bucket[(size_t)bin3 * CAP + s3] = base + 3;
    } else {
        for (int e = base; e < N_EDGES; ++e) {
            const int g = batch[col[e]];
            const int bin = set * NUM_GRAPHS + g;
            const int s = atomicAdd(&cursors[bin], 1);
            if (s < CAP) bucket[(size_t)bin * CAP + s] = e;
        }
    }
}

// ---------------- kernel 2: node aggregate (batch sorted -> binary search, float4) ----
__global__ __launch_bounds__(512) void node_agg_kernel(const float* __restrict__ x,
                                                       const int* __restrict__ batch,
                                                       float* __restrict__ node_agg) {
    const int g = blockIdx.x;
    int l = 0, r = N_NODES;
    while (l < r) { int m = (l + r) >> 1; if (batch[m] < g) l = m + 1; else r = m; }
    const int lo = l;
    r = N_NODES;
    while (l < r) { int m = (l + r) >> 1; if (batch[m] < g + 1) l = m + 1; else r = m; }
    const int hi = l;

    const int t = threadIdx.x;
    const int d4 = t & 31;   // float4 column (32 * 4 = 128 floats)
    const int rr = t >> 5;   // 0..15 row phase
    const float4* x4 = reinterpret_cast<const float4*>(x);

    float4 a = make_float4(0.f, 0.f, 0.f, 0.f);
    for (int i = lo + rr; i < hi; i += 16) {
        float4 v = x4[(size_t)i * 32 + d4];
        a.x += v.x; a.y += v.y; a.z += v.z; a.w += v.w;
    }

    __shared__ float4 red[512];
    red[t] = a;
    __syncthreads();
    if (t < 32) {
        float4 s = red[t];
        #pragma unroll
        for (int p = 1; p < 16; ++p) {
            float4 v = red[p * 32 + t];
            s.x += v.x; s.y += v.y; s.z += v.z; s.w += v.w;
        }
        reinterpret_cast<float4*>(node_agg)[g * 32 + t] = s;
    }
}

// ---------------- kernel 3: gather-sum edges per graph (NO atomics, register acc) -----
__global__ __launch_bounds__(512) void gather_kernel(const float* __restrict__ edge_attr,
                                                     const int* __restrict__ cursors,
                                                     const int* __restrict__ bucket,
                                                     float* __restrict__ edge_agg) {
    const int g = blockIdx.x;
    const int t = threadIdx.x;
    const int slot0 = t >> 3;      // 0..63
    const int dq = t & 7;          // float4 column
    const float4* ea4 = reinterpret_cast<const float4*>(edge_attr);

    float4 a0 = make_float4(0.f, 0.f, 0.f, 0.f);
    float4 a1 = make_float4(0.f, 0.f, 0.f, 0.f);

    for (int set = 0; set < NSET; ++set) {
        const int bin = set * NUM_GRAPHS + g;
        const int n = min(cursors[bin], CAP);
        const int* brow = bucket + (size_t)bin * CAP;
        for (int base = 0; base < n; base += 128) {
            const int s0 = base + slot0;
            const int s1 = s0 + 64;
            const int id0 = (s0 < n) ? brow[s0] : -1;
            const int id1 = (s1 < n) ? brow[s1] : -1;
            if (id0 >= 0) {
                const float4 v = ea4[(size_t)id0 * 8 + dq];
                a0.x += v.x; a0.y += v.y; a0.z += v.z; a0.w += v.w;
            }
            if (id1 >= 0) {
                const float4 v = ea4[(size_t)id1 * 8 + dq];
                a1.x += v.x; a1.y += v.y; a1.z += v.z; a1.w += v.w;
            }
        }
    }
    a0.x += a1.x; a0.y += a1.y; a0.z += a1.z; a0.w += a1.w;

    __shared__ float4 red[512];
    __shared__ float4 red2[64];
    red[t] = a0;
    __syncthreads();
    if (t < 64) {                    // t = part*8 + dq2
        const int dq2 = t & 7, part = t >> 3;
        float4 s = make_float4(0.f, 0.f, 0.f, 0.f);
        #pragma unroll
        for (int k = 0; k < 8; ++k) {
            const float4 v = red[(part * 8 + k) * 8 + dq2];
            s.x += v.x; s.y += v.y; s.z += v.z; s.w += v.w;
        }
        red2[t] = s;
    }
    __syncthreads();
    if (t < 8) {                     // dq = t
        float4 s = red2[t];
        #pragma unroll
        for (int k = 1; k < 8; ++k) {
            const float4 v = red2[k * 8 + t];
            s.x += v.x; s.y += v.y; s.z += v.z; s.w += v.w;
        }
        reinterpret_cast<float4*>(edge_agg + g * D_EDGE)[t] = s;
    }
}

// ---------------- kernel 4: tiny GEMM: out[g] = [node_agg|edge_agg] @ W + b -----------
__global__ __launch_bounds__(64) void gemm_kernel(const float* __restrict__ node_agg,
                                                  const float* __restrict__ edge_agg,
                                                  const float* __restrict__ W,
                                                  const float* __restrict__ b,
                                                  float* __restrict__ out) {
    const int g = blockIdx.x;
    const int t = threadIdx.x;       // output column
    __shared__ float feat[D_NODE + D_EDGE];
    for (int i = t; i < D_NODE; i += 64) feat[i] = node_agg[g * D_NODE + i];
    if (t < D_EDGE) feat[D_NODE + t] = edge_agg[g * D_EDGE + t];
    __syncthreads();

    float o = b[t];
    #pragma unroll 8
    for (int k = 0; k < D_NODE + D_EDGE; ++k)
        o += feat[k] * W[k * D_OUT + t];     // W L2-hot (41 KB), 256B coalesced per k
    out[g * D_OUT + t] = o;
}

extern "C" void kernel_launch(void* const* d_in, const int* in_sizes, int n_in,
                              void* d_out, int out_size, void* d_ws, size_t ws_size,
                              hipStream_t stream) {
    const float* x          = (const float*)d_in[0];
    const int*   edge_index = (const int*)d_in[1];
    const float* edge_attr  = (const float*)d_in[2];
    // d_in[3] = u, unused by the reference output
    const int*   batch      = (const int*)d_in[4];
    const float* W          = (const float*)d_in[5];
    const float* b          = (const float*)d_in[6];
    float* out = (float*)d_out;

    const int* col = edge_index + N_EDGES;   // row 1 of edge_index

    // workspace layout (~12.9 MB)
    int*   cursors  = (int*)d_ws;                                   // 4096 ints = 16 KB
    int*   bucket   = cursors + NBINS;                              // 4096*768 ints = 12.58 MB
    float* node_agg = (float*)(bucket + (size_t)NBINS * CAP);       // 256 KB
    float* edge_agg = node_agg + NUM_GRAPHS * D_NODE;               // 64 KB

    zero_kernel<<<(NBINS + 255) / 256, 256, 0, stream>>>(cursors);
    const int sc_blocks = (N_EDGES / 4 + 255) / 256;                // 1563
    scatter_kernel<<<sc_blocks, 256, 0, stream>>>(col, batch, cursors, bucket);
    node_agg_kernel<<<NUM_GRAPHS, 512, 0, stream>>>(x, batch, node_agg);
    gather_kernel<<<NUM_GRAPHS, 512, 0, stream>>>(edge_attr, cursors, bucket, edge_agg);
    gemm_kernel<<<NUM_GRAPHS, 64, 0, stream>>>(node_agg, edge_agg, W, b, out);
}

// Round 8
// 139.418 us; speedup vs baseline: 1.3896x; 1.3896x over previous
//
#include <hip/hip_runtime.h>

#define NUM_GRAPHS 512
#define N_NODES 100000
#define N_EDGES 1600000
#define D_NODE 128
#define D_EDGE 32
#define D_OUT 64

#define NSET 64                     // bucket sets: 32768 bins -> ~24 same-address RMWs per cursor
#define CAP 128                     // slots per (set,graph) bin; mean ~49, sigma ~8 -> ~10 sigma margin
#define NBINS (NSET * NUM_GRAPHS)   // 32768

// ---------------- kernel 0: zero the cursors (graph-capture-safe init) ----------------
__global__ __launch_bounds__(256) void zero_kernel(int* __restrict__ cursors) {
    const int t = blockIdx.x * 256 + threadIdx.x;
    if (t < NBINS) cursors[t] = 0;
}

// ---------------- kernel 1: scatter edge ids into per-(set,graph) buckets -------------
// 4 edges per thread; set = blockIdx&63 spreads the per-address atomic chains 64-wide.
__global__ __launch_bounds__(256) void scatter_kernel(const int* __restrict__ col,
                                                      const int* __restrict__ batch,
                                                      int* __restrict__ cursors,
                                                      int* __restrict__ bucket) {
    const int base = (blockIdx.x * 256 + threadIdx.x) * 4;
    const int set = blockIdx.x & (NSET - 1);
    if (base + 3 < N_EDGES) {
        const int4 c = *reinterpret_cast<const int4*>(col + base);
        const int g0 = batch[c.x];
        const int g1 = batch[c.y];
        const int g2 = batch[c.z];
        const int g3 = batch[c.w];
        const int bin0 = set * NUM_GRAPHS + g0;
        const int bin1 = set * NUM_GRAPHS + g1;
        const int bin2 = set * NUM_GRAPHS + g2;
        const int bin3 = set * NUM_GRAPHS + g3;
        const int s0 = atomicAdd(&cursors[bin0], 1);
        const int s1 = atomicAdd(&cursors[bin1], 1);
        const int s2 = atomicAdd(&cursors[bin2], 1);
        const int s3 = atomicAdd(&cursors[bin3], 1);
        if (s0 < CAP) bucket[(size_t)bin0 * CAP + s0] = base + 0;
        if (s1 < CAP) bucket[(size_t)bin1 * CAP + s1] = base + 1;
        if (s2 < CAP) bucket[(size_t)bin2 * CAP + s2] = base + 2;
        if (s3 < CAP) bucket[(size_t)bin3 * CAP + s3] = base + 3;
    } else {
        for (int e = base; e < N_EDGES; ++e) {
            const int g = batch[col[e]];
            const int bin = set * NUM_GRAPHS + g;
            const int s = atomicAdd(&cursors[bin], 1);
            if (s < CAP) bucket[(size_t)bin * CAP + s] = e;
        }
    }
}

// ---------------- kernel 2: node aggregate (batch sorted -> binary search, float4) ----
__global__ __launch_bounds__(512) void node_agg_kernel(const float* __restrict__ x,
                                                       const int* __restrict__ batch,
                                                       float* __restrict__ node_agg) {
    const int g = blockIdx.x;
    int l = 0, r = N_NODES;
    while (l < r) { int m = (l + r) >> 1; if (batch[m] < g) l = m + 1; else r = m; }
    const int lo = l;
    r = N_NODES;
    while (l < r) { int m = (l + r) >> 1; if (batch[m] < g + 1) l = m + 1; else r = m; }
    const int hi = l;

    const int t = threadIdx.x;
    const int d4 = t & 31;   // float4 column (32 * 4 = 128 floats)
    const int rr = t >> 5;   // 0..15 row phase
    const float4* x4 = reinterpret_cast<const float4*>(x);

    float4 a = make_float4(0.f, 0.f, 0.f, 0.f);
    for (int i = lo + rr; i < hi; i += 16) {
        float4 v = x4[(size_t)i * 32 + d4];
        a.x += v.x; a.y += v.y; a.z += v.z; a.w += v.w;
    }

    __shared__ float4 red[512];
    red[t] = a;
    __syncthreads();
    if (t < 32) {
        float4 s = red[t];
        #pragma unroll
        for (int p = 1; p < 16; ++p) {
            float4 v = red[p * 32 + t];
            s.x += v.x; s.y += v.y; s.z += v.z; s.w += v.w;
        }
        reinterpret_cast<float4*>(node_agg)[g * 32 + t] = s;
    }
}

// ---------------- kernel 3: gather-sum edges per graph (NO atomics, register acc) -----
__global__ __launch_bounds__(512) void gather_kernel(const float* __restrict__ edge_attr,
                                                     const int* __restrict__ cursors,
                                                     const int* __restrict__ bucket,
                                                     float* __restrict__ edge_agg) {
    const int g = blockIdx.x;
    const int t = threadIdx.x;
    const int slot0 = t >> 3;      // 0..63
    const int dq = t & 7;          // float4 column
    const float4* ea4 = reinterpret_cast<const float4*>(edge_attr);

    float4 a0 = make_float4(0.f, 0.f, 0.f, 0.f);
    float4 a1 = make_float4(0.f, 0.f, 0.f, 0.f);

    for (int set = 0; set < NSET; ++set) {
        const int bin = set * NUM_GRAPHS + g;
        const int n = min(cursors[bin], CAP);
        const int* brow = bucket + (size_t)bin * CAP;
        for (int base = 0; base < n; base += 128) {
            const int s0 = base + slot0;
            const int s1 = s0 + 64;
            const int id0 = (s0 < n) ? brow[s0] : -1;
            const int id1 = (s1 < n) ? brow[s1] : -1;
            if (id0 >= 0) {
                const float4 v = ea4[(size_t)id0 * 8 + dq];
                a0.x += v.x; a0.y += v.y; a0.z += v.z; a0.w += v.w;
            }
            if (id1 >= 0) {
                const float4 v = ea4[(size_t)id1 * 8 + dq];
                a1.x += v.x; a1.y += v.y; a1.z += v.z; a1.w += v.w;
            }
        }
    }
    a0.x += a1.x; a0.y += a1.y; a0.z += a1.z; a0.w += a1.w;

    __shared__ float4 red[512];
    __shared__ float4 red2[64];
    red[t] = a0;
    __syncthreads();
    if (t < 64) {                    // t = part*8 + dq2
        const int dq2 = t & 7, part = t >> 3;
        float4 s = make_float4(0.f, 0.f, 0.f, 0.f);
        #pragma unroll
        for (int k = 0; k < 8; ++k) {
            const float4 v = red[(part * 8 + k) * 8 + dq2];
            s.x += v.x; s.y += v.y; s.z += v.z; s.w += v.w;
        }
        red2[t] = s;
    }
    __syncthreads();
    if (t < 8) {                     // dq = t
        float4 s = red2[t];
        #pragma unroll
        for (int k = 1; k < 8; ++k) {
            const float4 v = red2[k * 8 + t];
            s.x += v.x; s.y += v.y; s.z += v.z; s.w += v.w;
        }
        reinterpret_cast<float4*>(edge_agg + g * D_EDGE)[t] = s;
    }
}

// ---------------- kernel 4: tiny GEMM: out[g] = [node_agg|edge_agg] @ W + b -----------
__global__ __launch_bounds__(64) void gemm_kernel(const float* __restrict__ node_agg,
                                                  const float* __restrict__ edge_agg,
                                                  const float* __restrict__ W,
                                                  const float* __restrict__ b,
                                                  float* __restrict__ out) {
    const int g = blockIdx.x;
    const int t = threadIdx.x;       // output column
    __shared__ float feat[D_NODE + D_EDGE];
    for (int i = t; i < D_NODE; i += 64) feat[i] = node_agg[g * D_NODE + i];
    if (t < D_EDGE) feat[D_NODE + t] = edge_agg[g * D_EDGE + t];
    __syncthreads();

    float o = b[t];
    #pragma unroll 8
    for (int k = 0; k < D_NODE + D_EDGE; ++k)
        o += feat[k] * W[k * D_OUT + t];     // W L2-hot (41 KB), 256B coalesced per k
    out[g * D_OUT + t] = o;
}

extern "C" void kernel_launch(void* const* d_in, const int* in_sizes, int n_in,
                              void* d_out, int out_size, void* d_ws, size_t ws_size,
                              hipStream_t stream) {
    const float* x          = (const float*)d_in[0];
    const int*   edge_index = (const int*)d_in[1];
    const float* edge_attr  = (const float*)d_in[2];
    // d_in[3] = u, unused by the reference output
    const int*   batch      = (const int*)d_in[4];
    const float* W          = (const float*)d_in[5];
    const float* b          = (const float*)d_in[6];
    float* out = (float*)d_out;

    const int* col = edge_index + N_EDGES;   // row 1 of edge_index

    // workspace layout (~17.2 MB)
    int*   cursors  = (int*)d_ws;                                   // 32768 ints = 128 KB
    int*   bucket   = cursors + NBINS;                              // 32768*128 ints = 16.78 MB
    float* node_agg = (float*)(bucket + (size_t)NBINS * CAP);       // 256 KB
    float* edge_agg = node_agg + NUM_GRAPHS * D_NODE;               // 64 KB

    zero_kernel<<<(NBINS + 255) / 256, 256, 0, stream>>>(cursors);
    const int sc_blocks = (N_EDGES / 4 + 255) / 256;                // 1563
    scatter_kernel<<<sc_blocks, 256, 0, stream>>>(col, batch, cursors, bucket);
    node_agg_kernel<<<NUM_GRAPHS, 512, 0, stream>>>(x, batch, node_agg);
    gather_kernel<<<NUM_GRAPHS, 512, 0, stream>>>(edge_attr, cursors, bucket, edge_agg);
    gemm_kernel<<<NUM_GRAPHS, 64, 0, stream>>>(node_agg, edge_agg, W, b, out);
}

// Round 9
// 89.350 us; speedup vs baseline: 2.1682x; 1.5604x over previous
//
#include <hip/hip_runtime.h>

#define NUM_GRAPHS 512
#define N_NODES 100000
#define N_EDGES 1600000
#define D_NODE 128
#define D_EDGE 32
#define D_OUT 64

#define NBLK 512                 // count/place blocks
#define EPB (N_EDGES / NBLK)     // 3125 edges per block (exact)
#define GCAP 5120                // per-graph bucket cap: deg mean 3125, sigma ~224 -> ~8.9 sigma

// ---------------- kernel 1: count per-(block,graph) + materialize eg ------------------
__global__ __launch_bounds__(256) void count_kernel(const int* __restrict__ col,
                                                    const int* __restrict__ batch,
                                                    int* __restrict__ eg,
                                                    int* __restrict__ cnt) {
    __shared__ int c[NUM_GRAPHS];
    const int t = threadIdx.x;
    const int b = blockIdx.x;
    c[t] = 0; c[t + 256] = 0;
    __syncthreads();
    const int base = b * EPB;
    #pragma unroll
    for (int k = 0; k < 6; ++k) {                 // 6*512 = 3072 edges, pairwise independent
        const int i0 = k * 512 + t, i1 = i0 + 256;
        const int c0 = col[base + i0], c1 = col[base + i1];
        const int g0 = batch[c0], g1 = batch[c1]; // two independent gathers in flight
        eg[base + i0] = g0; eg[base + i1] = g1;
        atomicAdd(&c[g0], 1); atomicAdd(&c[g1], 1);
    }
    if (t < EPB - 3072) {                         // 53 remainder
        const int i = 3072 + t;
        const int g = batch[col[base + i]];
        eg[base + i] = g;
        atomicAdd(&c[g], 1);
    }
    __syncthreads();
    cnt[b * NUM_GRAPHS + t]       = c[t];         // coalesced [b][g] write
    cnt[b * NUM_GRAPHS + t + 256] = c[t + 256];
}

// ---------------- kernel 2: per-graph exclusive scan over blocks (no device atomics) --
__global__ __launch_bounds__(NBLK) void scan_kernel(const int* __restrict__ cnt,
                                                    int* __restrict__ pos,
                                                    int* __restrict__ totals) {
    const int g = blockIdx.x;
    const int t = threadIdx.x;                    // t indexes count-block b
    __shared__ int sc[NBLK];
    const int v = cnt[t * NUM_GRAPHS + g];
    sc[t] = v;
    __syncthreads();
    for (int off = 1; off < NBLK; off <<= 1) {    // Hillis-Steele inclusive scan
        const int x = (t >= off) ? sc[t - off] : 0;
        __syncthreads();
        sc[t] += x;
        __syncthreads();
    }
    pos[t * NUM_GRAPHS + g] = g * GCAP + (sc[t] - v);   // absolute exclusive prefix
    if (t == NBLK - 1) totals[g] = sc[t];
}

// ---------------- kernel 3: place edge ids into dense per-graph rows ------------------
__global__ __launch_bounds__(256) void place_kernel(const int* __restrict__ eg,
                                                    const int* __restrict__ pos,
                                                    int* __restrict__ bucket) {
    __shared__ int cur[NUM_GRAPHS];
    const int t = threadIdx.x;
    const int b = blockIdx.x;
    cur[t]       = pos[b * NUM_GRAPHS + t];       // coalesced [b][g] read
    cur[t + 256] = pos[b * NUM_GRAPHS + t + 256];
    __syncthreads();
    const int base = b * EPB;
    #pragma unroll
    for (int k = 0; k < 6; ++k) {
        const int i0 = k * 512 + t, i1 = i0 + 256;
        const int g0 = eg[base + i0], g1 = eg[base + i1];   // coalesced, no gather
        const int s0 = atomicAdd(&cur[g0], 1);
        const int s1 = atomicAdd(&cur[g1], 1);
        bucket[s0] = base + i0;
        bucket[s1] = base + i1;
    }
    if (t < EPB - 3072) {
        const int i = 3072 + t;
        const int g = eg[base + i];
        bucket[atomicAdd(&cur[g], 1)] = base + i;
    }
}

// ---------------- kernel 4: fused node-sum + edge gather-sum + tiny GEMM --------------
__global__ __launch_bounds__(512) void fused_kernel(const float* __restrict__ x,
                                                    const int* __restrict__ batch,
                                                    const float* __restrict__ edge_attr,
                                                    const int* __restrict__ totals,
                                                    const int* __restrict__ bucket,
                                                    const float* __restrict__ W,
                                                    const float* __restrict__ bias,
                                                    float* __restrict__ out) {
    const int g = blockIdx.x;
    const int t = threadIdx.x;
    __shared__ int ids[GCAP];                     // 20 KB
    __shared__ float4 red[512];                   // 8 KB (reused node then edge)
    __shared__ float4 red2[64];
    __shared__ __align__(16) float feat[D_NODE + D_EDGE];

    // issue dense id copy first so its loads overlap the node phase
    const int ntot = min(totals[g], GCAP);
    for (int i = t; i < ntot; i += 512) ids[i] = bucket[g * GCAP + i];   // coalesced

    // node range via binary search (batch sorted)
    int l = 0, r = N_NODES;
    while (l < r) { int m = (l + r) >> 1; if (batch[m] < g) l = m + 1; else r = m; }
    const int lo = l;
    r = N_NODES;
    while (l < r) { int m = (l + r) >> 1; if (batch[m] < g + 1) l = m + 1; else r = m; }
    const int hi = l;

    // node phase: thread (rr = t>>5 row phase, d4 = t&31 float4 col)
    const float4* x4 = reinterpret_cast<const float4*>(x);
    const int d4 = t & 31, rr = t >> 5;
    float4 a = make_float4(0.f, 0.f, 0.f, 0.f);
    for (int i = lo + rr; i < hi; i += 16) {
        const float4 v = x4[(size_t)i * 32 + d4];
        a.x += v.x; a.y += v.y; a.z += v.z; a.w += v.w;
    }
    red[t] = a;
    __syncthreads();                              // also guarantees ids[] complete
    if (t < 32) {
        float4 s = red[t];
        #pragma unroll
        for (int p = 1; p < 16; ++p) {
            const float4 v = red[p * 32 + t];
            s.x += v.x; s.y += v.y; s.z += v.z; s.w += v.w;
        }
        reinterpret_cast<float4*>(feat)[t] = s;   // feat[0..127]
    }

    // edge phase: thread (slot0 = t>>3, dq = t&7); 4 independent gather chains
    const float4* ea4 = reinterpret_cast<const float4*>(edge_attr);
    const int slot0 = t >> 3, dq = t & 7;
    float4 a0 = make_float4(0.f, 0.f, 0.f, 0.f);
    float4 a1 = make_float4(0.f, 0.f, 0.f, 0.f);
    float4 a2 = make_float4(0.f, 0.f, 0.f, 0.f);
    float4 a3 = make_float4(0.f, 0.f, 0.f, 0.f);
    for (int base = 0; base < ntot; base += 256) {
        const int s0 = base + slot0, s1 = s0 + 64, s2 = s0 + 128, s3 = s0 + 192;
        const int id0 = (s0 < ntot) ? ids[s0] : -1;
        const int id1 = (s1 < ntot) ? ids[s1] : -1;
        const int id2 = (s2 < ntot) ? ids[s2] : -1;
        const int id3 = (s3 < ntot) ? ids[s3] : -1;
        if (id0 >= 0) { const float4 v = ea4[(size_t)id0 * 8 + dq]; a0.x += v.x; a0.y += v.y; a0.z += v.z; a0.w += v.w; }
        if (id1 >= 0) { const float4 v = ea4[(size_t)id1 * 8 + dq]; a1.x += v.x; a1.y += v.y; a1.z += v.z; a1.w += v.w; }
        if (id2 >= 0) { const float4 v = ea4[(size_t)id2 * 8 + dq]; a2.x += v.x; a2.y += v.y; a2.z += v.z; a2.w += v.w; }
        if (id3 >= 0) { const float4 v = ea4[(size_t)id3 * 8 + dq]; a3.x += v.x; a3.y += v.y; a3.z += v.z; a3.w += v.w; }
    }
    a0.x += a1.x + a2.x + a3.x;
    a0.y += a1.y + a2.y + a3.y;
    a0.z += a1.z + a2.z + a3.z;
    a0.w += a1.w + a2.w + a3.w;
    __syncthreads();                              // t<32 done reading red (node reduce)
    red[t] = a0;                                  // red[slot0*8+dq]
    __syncthreads();
    if (t < 64) {                                 // part = t>>3, dq2 = t&7
        const int part = t >> 3, dq2 = t & 7;
        float4 s = make_float4(0.f, 0.f, 0.f, 0.f);
        #pragma unroll
        for (int k = 0; k < 8; ++k) {
            const float4 v = red[(part * 8 + k) * 8 + dq2];
            s.x += v.x; s.y += v.y; s.z += v.z; s.w += v.w;
        }
        red2[t] = s;
    }
    __syncthreads();
    if (t < 8) {
        float4 s = red2[t];
        #pragma unroll
        for (int k = 1; k < 8; ++k) {
            const float4 v = red2[k * 8 + t];
            s.x += v.x; s.y += v.y; s.z += v.z; s.w += v.w;
        }
        reinterpret_cast<float4*>(feat + D_NODE)[t] = s;   // feat[128..159]
    }
    __syncthreads();

    // gemm phase: out[g][t] for t < 64
    if (t < D_OUT) {
        float o = bias[t];
        #pragma unroll 8
        for (int k = 0; k < D_NODE + D_EDGE; ++k)
            o += feat[k] * W[k * D_OUT + t];      // W (41 KB) L2/L3-hot, coalesced per k
        out[g * D_OUT + t] = o;
    }
}

extern "C" void kernel_launch(void* const* d_in, const int* in_sizes, int n_in,
                              void* d_out, int out_size, void* d_ws, size_t ws_size,
                              hipStream_t stream) {
    const float* x          = (const float*)d_in[0];
    const int*   edge_index = (const int*)d_in[1];
    const float* edge_attr  = (const float*)d_in[2];
    // d_in[3] = u, unused by the reference output
    const int*   batch      = (const int*)d_in[4];
    const float* W          = (const float*)d_in[5];
    const float* b          = (const float*)d_in[6];
    float* out = (float*)d_out;

    const int* col = edge_index + N_EDGES;   // row 1 of edge_index

    // workspace layout (~21.4 MB)
    int* eg     = (int*)d_ws;                                  // 1.6M ints   = 6.4 MB
    int* cnt    = eg + N_EDGES;                                // 512*512     = 1.05 MB
    int* pos    = cnt + NBLK * NUM_GRAPHS;                     // 512*512     = 1.05 MB
    int* totals = pos + NBLK * NUM_GRAPHS;                     // 512 ints
    int* bucket = totals + NUM_GRAPHS;                         // 512*5120    = 10.5 MB

    count_kernel<<<NBLK, 256, 0, stream>>>(col, batch, eg, cnt);
    scan_kernel<<<NUM_GRAPHS, NBLK, 0, stream>>>(cnt, pos, totals);
    place_kernel<<<NBLK, 256, 0, stream>>>(eg, pos, bucket);
    fused_kernel<<<NUM_GRAPHS, 512, 0, stream>>>(x, batch, edge_attr, totals, bucket, W, b, out);
}